// Round 2
// 854.885 us; speedup vs baseline: 1.0084x; 1.0084x over previous
//
#include <hip/hip_runtime.h>

#define K_ITER   30
#define MU       0.01f
#define EPS      1e-6f
#define MAX_LS   25
#define FULLMASK 0x01FFFFFFu
#define MM       128
#define NN       256
#define NPROB    512
#define NTHR     512          // 8 waves/block; launch_bounds(512,4) -> 2 blocks/CU guaranteed
#define DONEBIT  0x80000000u

// ws layout (unsigned words), each region padded to its own cache lines
#define W_GM    0             // gmask[k]: running AND of 25-bit acceptance masks
#define W_CNT   64            // cnt[k]:   arrival counter
#define W_RES   128           // res[k]:   published {DONEBIT | final mask}

// --- cross-lane reduce helpers -------------------------------------------
#define RED16_ADD(v) do { v += __shfl_xor(v, 1); v += __shfl_xor(v, 2); \
                          v += __shfl_xor(v, 4); v += __shfl_xor(v, 8); } while (0)
#define REDG_ADD(v)  do { v += __shfl_xor(v, 16); v += __shfl_xor(v, 32); } while (0)
#define RED64_AND(v) do { v &= __shfl_xor(v, 1);  v &= __shfl_xor(v, 2);  v &= __shfl_xor(v, 4); \
                          v &= __shfl_xor(v, 8);  v &= __shfl_xor(v, 16); v &= __shfl_xor(v, 32); } while (0)
#define RED64_MIN(v) do { v = fminf(v, __shfl_xor(v, 1));  v = fminf(v, __shfl_xor(v, 2)); \
                          v = fminf(v, __shfl_xor(v, 4));  v = fminf(v, __shfl_xor(v, 8)); \
                          v = fminf(v, __shfl_xor(v, 16)); v = fminf(v, __shfl_xor(v, 32)); } while (0)

// -------------------------------------------------------- ws init ----
__global__ void lbp_ws_init(unsigned* __restrict__ wsu)
{
    const int t = threadIdx.x;
    if (t < K_ITER) {
        wsu[W_GM  + t] = 0xFFFFFFFFu;
        wsu[W_CNT + t] = 0u;
        wsu[W_RES + t] = 0u;
    }
}

// Persistent kernel: block p owns problem p; A slice lives in 64 VGPRs/thread
// for the whole solve.  Lane (g=lane>>4, j=lane&15) of wave w holds rows
// 16w+4g+r (r=0..3) and col chunks [4j+64c .. 4j+64c+3] (c=0..3).
// Grid-wide step consensus per iteration via device-scope atomics + release
// barrier (512 blocks == guaranteed co-resident capacity at 2 blocks/CU).
__global__ __launch_bounds__(NTHR, 4)
void lbp_fused(const float* __restrict__ xraw_g,
               const float* __restrict__ A_g,
               const float* __restrict__ b_g,
               const float* __restrict__ lower_g,
               float* __restrict__ out_g,
               unsigned* __restrict__ wsu)
{
    const int p    = blockIdx.x;
    const int t    = threadIdx.x;
    const int lane = t & 63;
    const int wave = t >> 6;          // 0..7
    const int g    = lane >> 4;       // 0..3  row sub-group
    const int j    = lane & 15;       // 0..15 col sub-group
    const int wb   = wave * 16;       // wave's base row

    const float* A = A_g + (size_t)p * (MM * NN);

    __shared__ __align__(16) float s_x[NN];
    __shared__ __align__(16) float s_grad[NN];
    __shared__ __align__(16) float s_xraw[NN];
    __shared__ __align__(16) float s_lower[NN];
    __shared__ __align__(16) float s_p1[8][NN];            // per-wave A^T w partials
    __shared__ float s_bb[MM], s_cl[MM], s_ce[MM], s_w[MM];
    __shared__ float s_axc[MM], s_pg[MM], s_px[MM];
    __shared__ float s_rs[MM], s_al[MM], s_ssq[MM];        // init only
    __shared__ float s_redw[2];
    __shared__ unsigned s_mask;
    __shared__ float s_step, s_t0;

    // ---- load A slice into registers (only HBM read of A in the solve) ----
    float4 a[4][4];
    {
        const float* base = A + (size_t)(wb + 4 * g) * NN + 4 * j;
        #pragma unroll
        for (int r = 0; r < 4; ++r)
            #pragma unroll
            for (int c = 0; c < 4; ++c)
                a[r][c] = *(const float4*)(base + r * NN + 64 * c);
    }

    if (t < NN) { s_xraw[t] = xraw_g[p * NN + t]; s_lower[t] = lower_g[p * NN + t]; }
    if (t < MM) s_bb[t] = b_g[p * MM + t];
    __syncthreads();

    // ---- init: row stats (ssq, rowsum, A·lower) from registers ----
    {
        float ssq[4] = {0.f,0.f,0.f,0.f}, rs[4] = {0.f,0.f,0.f,0.f}, al[4] = {0.f,0.f,0.f,0.f};
        #pragma unroll
        for (int c = 0; c < 4; ++c) {
            const float4 lo4 = ((const float4*)s_lower)[j + 16 * c];
            #pragma unroll
            for (int r = 0; r < 4; ++r) {
                const float4 av = a[r][c];
                ssq[r] += av.x*av.x + av.y*av.y + av.z*av.z + av.w*av.w;
                rs[r]  += av.x + av.y + av.z + av.w;
                al[r]  += av.x*lo4.x + av.y*lo4.y + av.z*lo4.z + av.w*lo4.w;
            }
        }
        #pragma unroll
        for (int r = 0; r < 4; ++r) {
            RED16_ADD(ssq[r]); RED16_ADD(rs[r]); RED16_ADD(al[r]);
            if (j == 0) {
                const int m = wb + 4 * g + r;
                s_ssq[m] = ssq[r]; s_rs[m] = rs[r]; s_al[m] = al[r];
            }
        }
    }
    __syncthreads();

    if (t < MM) {
        const float r = fmaxf(sqrtf(s_ssq[t]), 1e-12f);
        s_cl[t] = 1e-12f * r;                    // slack clamp (unnormalized)
        s_ce[t] = s_bb[t] - EPS * r;             // feasibility threshold
        const float adw = s_rs[t] / r;
        const float sw  = (s_bb[t] - s_al[t]) / r;
        float ratio = (adw > 0.f) ? (sw / fmaxf(adw, 1e-12f)) : INFINITY;
        RED64_MIN(ratio);
        if (lane == 0) s_redw[wave] = ratio;
    }
    __syncthreads();
    if (t == 0) s_t0 = fmaxf(0.5f * fminf(s_redw[0], s_redw[1]), 2.0f * EPS);
    __syncthreads();
    const float t0 = s_t0;
    if (t < NN) s_x[t]   = s_lower[t] + t0;
    if (t < MM) s_axc[t] = s_al[t] + t0 * s_rs[t];

    // feasibility repair (faithful; no-op for these inputs)
    int okf = 1;
    if (t < MM) okf = okf && (s_axc[t] <= s_ce[t]);
    if (t < NN) okf = okf && (s_x[t] >= s_lower[t] + EPS);
    const int feas = __syncthreads_and(okf);
    if (!feas) {
        if (t < NN) s_x[t] = 0.5f * (fmaxf(s_x[t], 0.f) + s_lower[t]);
        __syncthreads();
        float axp[4] = {0.f,0.f,0.f,0.f};
        #pragma unroll
        for (int c = 0; c < 4; ++c) {
            const float4 x4 = ((const float4*)s_x)[j + 16 * c];
            #pragma unroll
            for (int r = 0; r < 4; ++r) {
                const float4 av = a[r][c];
                axp[r] += av.x*x4.x + av.y*x4.y + av.z*x4.z + av.w*x4.w;
            }
        }
        #pragma unroll
        for (int r = 0; r < 4; ++r) {
            RED16_ADD(axp[r]);
            if (j == 0) s_axc[wb + 4 * g + r] = axp[r];
        }
        __syncthreads();
    }

    // ------------------------------ main loop ------------------------------
    for (int k = 0; k < K_ITER; ++k) {
        if (t == 0) s_mask = 0xFFFFFFFFu;
        if (t < MM) s_w[t] = MU / fmaxf(s_bb[t] - s_axc[t], s_cl[t]);
        __syncthreads();

        // pass 1: gbar = A^T w  (registers, then shfl over g, then 8-wave LDS)
        {
            float4 gb[4];
            #pragma unroll
            for (int c = 0; c < 4; ++c) gb[c] = make_float4(0.f, 0.f, 0.f, 0.f);
            #pragma unroll
            for (int r = 0; r < 4; ++r) {
                const float wm = s_w[wb + 4 * g + r];
                #pragma unroll
                for (int c = 0; c < 4; ++c) {
                    gb[c].x += a[r][c].x * wm;
                    gb[c].y += a[r][c].y * wm;
                    gb[c].z += a[r][c].z * wm;
                    gb[c].w += a[r][c].w * wm;
                }
            }
            #pragma unroll
            for (int c = 0; c < 4; ++c) {
                REDG_ADD(gb[c].x); REDG_ADD(gb[c].y); REDG_ADD(gb[c].z); REDG_ADD(gb[c].w);
            }
            if (g == 0) {
                #pragma unroll
                for (int c = 0; c < 4; ++c)
                    ((float4*)s_p1[wave])[j + 16 * c] = gb[c];
            }
        }
        __syncthreads();

        // grad + n-side line-search mask
        if (t < NN) {
            float gsum = 0.f;
            #pragma unroll
            for (int w = 0; w < 8; ++w) gsum += s_p1[w][t];
            const float xt = s_x[t];
            const float gr = (xt - s_xraw[t]) + gsum + MU / fmaxf(xt - s_lower[t], 1e-12f);
            s_grad[t] = gr;
            unsigned mn = 0u;
            const float loe = s_lower[t] + EPS;
            float st = 1.0f;
            #pragma unroll
            for (int l = 0; l < MAX_LS; ++l) {
                if (xt - st * gr >= loe) mn |= (1u << l);
                st *= 0.5f;
            }
            RED64_AND(mn);
            if (lane == 0) atomicAnd(&s_mask, mn);
        }
        __syncthreads();

        // pass 2: pg = A*grad, px = A*x (fresh), from registers
        {
            float pg[4] = {0.f,0.f,0.f,0.f}, px[4] = {0.f,0.f,0.f,0.f};
            #pragma unroll
            for (int c = 0; c < 4; ++c) {
                const float4 g4 = ((const float4*)s_grad)[j + 16 * c];
                const float4 x4 = ((const float4*)s_x)[j + 16 * c];
                #pragma unroll
                for (int r = 0; r < 4; ++r) {
                    const float4 av = a[r][c];
                    pg[r] += av.x*g4.x + av.y*g4.y + av.z*g4.z + av.w*g4.w;
                    px[r] += av.x*x4.x + av.y*x4.y + av.z*x4.z + av.w*x4.w;
                }
            }
            #pragma unroll
            for (int r = 0; r < 4; ++r) {
                RED16_ADD(pg[r]); RED16_ADD(px[r]);
                if (j == 0) { const int m = wb + 4 * g + r; s_pg[m] = pg[r]; s_px[m] = px[r]; }
            }
        }
        __syncthreads();

        // m-side line-search mask
        if (t < MM) {
            const float pgm = s_pg[t], pxm = s_px[t], cem = s_ce[t];
            unsigned mmk = 0u;
            float st = 1.0f;
            #pragma unroll
            for (int l = 0; l < MAX_LS; ++l) {
                if (pxm - st * pgm <= cem) mmk |= (1u << l);
                st *= 0.5f;
            }
            RED64_AND(mmk);
            if (lane == 0) atomicAnd(&s_mask, mmk);
        }
        __syncthreads();

        // ---- grid-wide consensus: AND masks, count arrivals, publish ----
        if (t == 0) {
            const unsigned my = s_mask & FULLMASK;
            __hip_atomic_fetch_and(&wsu[W_GM + k], my,
                                   __ATOMIC_RELEASE, __HIP_MEMORY_SCOPE_AGENT);
            const unsigned arrived =
                __hip_atomic_fetch_add(&wsu[W_CNT + k], 1u,
                                       __ATOMIC_ACQ_REL, __HIP_MEMORY_SCOPE_AGENT);
            if (arrived == NPROB - 1u) {
                const unsigned gm =
                    __hip_atomic_load(&wsu[W_GM + k],
                                      __ATOMIC_ACQUIRE, __HIP_MEMORY_SCOPE_AGENT) & FULLMASK;
                __hip_atomic_store(&wsu[W_RES + k], gm | DONEBIT,
                                   __ATOMIC_RELEASE, __HIP_MEMORY_SCOPE_AGENT);
            }
            unsigned r;
            while (!((r = __hip_atomic_load(&wsu[W_RES + k],
                                            __ATOMIC_ACQUIRE, __HIP_MEMORY_SCOPE_AGENT)) & DONEBIT))
                __builtin_amdgcn_s_sleep(2);
            const unsigned gm = r & FULLMASK;
            s_step = gm ? ldexpf(1.0f, -(__ffs(gm) - 1)) : 0.0f;
        }
        __syncthreads();
        const float step = s_step;
        if (t < NN) s_x[t]  -= step * s_grad[t];
        if (t < MM) s_axc[t] = s_px[t] - step * s_pg[t];
        // next iteration's first __syncthreads orders these writes before reads
    }

    if (t < NN) out_g[p * NN + t] = fmaxf(s_x[t], 0.0f);
}

// -------------------------------------------------------------- launch ----
extern "C" void kernel_launch(void* const* d_in, const int* in_sizes, int n_in,
                              void* d_out, int out_size, void* d_ws, size_t ws_size,
                              hipStream_t stream) {
    const float* xraw  = (const float*)d_in[0];
    const float* A     = (const float*)d_in[1];
    const float* b     = (const float*)d_in[2];
    const float* lower = (const float*)d_in[3];
    float* out = (float*)d_out;
    unsigned* wsu = (unsigned*)d_ws;

    lbp_ws_init<<<1, 64, 0, stream>>>(wsu);
    lbp_fused<<<NPROB, NTHR, 0, stream>>>(xraw, A, b, lower, out, wsu);
}

// Round 3
// 332.500 us; speedup vs baseline: 2.5926x; 2.5711x over previous
//
#include <hip/hip_runtime.h>

#define K_ITER   30
#define MU       0.01f
#define EPS      1e-6f
#define MAX_LS   25
#define FULLMASK 0x01FFFFFFu
#define MM       128
#define NN       256
#define NPROB    512
#define NTHR     512          // 8 waves/block; launch_bounds(512,4) -> 2 blocks/CU guaranteed
#define DONEBIT  0x80000000u

// ---- ws layout (unsigned words); ALL words zero-initialized ----
// res[k]          : published {DONEBIT | final 25-bit mask}
// root_or[k]      : OR of cleared bits (32 leaf leaders)
// root_cnt[k]     : leaf-leader arrival count
// leaf[k][g]      : +0 OR of cleared bits, +8 arrival count (16 blocks/leaf)
#define LLINE 16
#define GRPS  32
#define GSZ   16
#define W_RES(k)      ((k)*LLINE)
#define W_ROOT_OR(k)  (K_ITER*LLINE + (k)*LLINE)
#define W_ROOT_CNT(k) (2*K_ITER*LLINE + (k)*LLINE)
#define W_LEAF(k,g)   (3*K_ITER*LLINE + ((k)*GRPS + (g))*LLINE)
#define W_END         (3*K_ITER*LLINE + K_ITER*GRPS*LLINE)   // 16800 words

// --- cross-lane reduce helpers -------------------------------------------
#define RED16_ADD(v) do { v += __shfl_xor(v, 1); v += __shfl_xor(v, 2); \
                          v += __shfl_xor(v, 4); v += __shfl_xor(v, 8); } while (0)
#define REDG_ADD(v)  do { v += __shfl_xor(v, 16); v += __shfl_xor(v, 32); } while (0)
#define RED64_AND(v) do { v &= __shfl_xor(v, 1);  v &= __shfl_xor(v, 2);  v &= __shfl_xor(v, 4); \
                          v &= __shfl_xor(v, 8);  v &= __shfl_xor(v, 16); v &= __shfl_xor(v, 32); } while (0)
#define RED64_MIN(v) do { v = fminf(v, __shfl_xor(v, 1));  v = fminf(v, __shfl_xor(v, 2)); \
                          v = fminf(v, __shfl_xor(v, 4));  v = fminf(v, __shfl_xor(v, 8)); \
                          v = fminf(v, __shfl_xor(v, 16)); v = fminf(v, __shfl_xor(v, 32)); } while (0)

// -------------------------------------------------------- ws clear ----
__global__ void lbp_ws_init(unsigned* __restrict__ wsu)
{
    const int idx = blockIdx.x * 1024 + threadIdx.x;
    if (idx < W_END) wsu[idx] = 0u;
}

// Persistent kernel: block p owns problem p; A slice lives in 64 regs/thread.
// Lane (g=lane>>4, j=lane&15) of wave w holds rows 16w+4g+r (r=0..3) and col
// chunks [4j+64c .. 4j+64c+3] (c=0..3).  Grid consensus per iteration via
// RELAXED agent-scope atomics (coherent at MALL via scope flag; no L2
// writeback/invalidate storms) + explicit vmcnt ordering + 2-level tree.
__global__ __launch_bounds__(NTHR, 4)
void lbp_fused(const float* __restrict__ xraw_g,
               const float* __restrict__ A_g,
               const float* __restrict__ b_g,
               const float* __restrict__ lower_g,
               float* __restrict__ out_g,
               unsigned* __restrict__ wsu)
{
    const int p    = blockIdx.x;
    const int t    = threadIdx.x;
    const int lane = t & 63;
    const int wave = t >> 6;          // 0..7
    const int g    = lane >> 4;       // 0..3  row sub-group
    const int j    = lane & 15;       // 0..15 col sub-group
    const int wb   = wave * 16;       // wave's base row

    const float* A = A_g + (size_t)p * (MM * NN);

    __shared__ __align__(16) float s_x[NN];
    __shared__ __align__(16) float s_grad[NN];
    __shared__ __align__(16) float s_xraw[NN];
    __shared__ __align__(16) float s_lower[NN];
    __shared__ __align__(16) float s_p1[8][NN];            // per-wave A^T w partials
    __shared__ float s_bb[MM], s_cl[MM], s_ce[MM], s_w[MM];
    __shared__ float s_axc[MM], s_pg[MM], s_px[MM];
    __shared__ float s_rs[MM], s_al[MM], s_ssq[MM];        // init only
    __shared__ float s_redw[2];
    __shared__ unsigned s_mask;
    __shared__ float s_step, s_t0;

    // ---- load A slice into registers (only HBM read of A in the solve) ----
    float4 a[4][4];
    {
        const float* base = A + (size_t)(wb + 4 * g) * NN + 4 * j;
        #pragma unroll
        for (int r = 0; r < 4; ++r)
            #pragma unroll
            for (int c = 0; c < 4; ++c)
                a[r][c] = *(const float4*)(base + r * NN + 64 * c);
    }

    if (t < NN) { s_xraw[t] = xraw_g[p * NN + t]; s_lower[t] = lower_g[p * NN + t]; }
    if (t < MM) s_bb[t] = b_g[p * MM + t];
    __syncthreads();

    // ---- init: row stats (ssq, rowsum, A·lower) from registers ----
    {
        float ssq[4] = {0.f,0.f,0.f,0.f}, rs[4] = {0.f,0.f,0.f,0.f}, al[4] = {0.f,0.f,0.f,0.f};
        #pragma unroll
        for (int c = 0; c < 4; ++c) {
            const float4 lo4 = ((const float4*)s_lower)[j + 16 * c];
            #pragma unroll
            for (int r = 0; r < 4; ++r) {
                const float4 av = a[r][c];
                ssq[r] += av.x*av.x + av.y*av.y + av.z*av.z + av.w*av.w;
                rs[r]  += av.x + av.y + av.z + av.w;
                al[r]  += av.x*lo4.x + av.y*lo4.y + av.z*lo4.z + av.w*lo4.w;
            }
        }
        #pragma unroll
        for (int r = 0; r < 4; ++r) {
            RED16_ADD(ssq[r]); RED16_ADD(rs[r]); RED16_ADD(al[r]);
            if (j == 0) {
                const int m = wb + 4 * g + r;
                s_ssq[m] = ssq[r]; s_rs[m] = rs[r]; s_al[m] = al[r];
            }
        }
    }
    __syncthreads();

    if (t < MM) {
        const float r = fmaxf(sqrtf(s_ssq[t]), 1e-12f);
        s_cl[t] = 1e-12f * r;                    // slack clamp (unnormalized)
        s_ce[t] = s_bb[t] - EPS * r;             // feasibility threshold
        const float adw = s_rs[t] / r;
        const float sw  = (s_bb[t] - s_al[t]) / r;
        float ratio = (adw > 0.f) ? (sw / fmaxf(adw, 1e-12f)) : INFINITY;
        RED64_MIN(ratio);
        if (lane == 0) s_redw[wave] = ratio;
    }
    __syncthreads();
    if (t == 0) s_t0 = fmaxf(0.5f * fminf(s_redw[0], s_redw[1]), 2.0f * EPS);
    __syncthreads();
    const float t0 = s_t0;
    if (t < NN) s_x[t]   = s_lower[t] + t0;
    if (t < MM) s_axc[t] = s_al[t] + t0 * s_rs[t];

    // feasibility repair (faithful; no-op for these inputs)
    int okf = 1;
    if (t < MM) okf = okf && (s_axc[t] <= s_ce[t]);
    if (t < NN) okf = okf && (s_x[t] >= s_lower[t] + EPS);
    const int feas = __syncthreads_and(okf);
    if (!feas) {
        if (t < NN) s_x[t] = 0.5f * (fmaxf(s_x[t], 0.f) + s_lower[t]);
        __syncthreads();
        float axp[4] = {0.f,0.f,0.f,0.f};
        #pragma unroll
        for (int c = 0; c < 4; ++c) {
            const float4 x4 = ((const float4*)s_x)[j + 16 * c];
            #pragma unroll
            for (int r = 0; r < 4; ++r) {
                const float4 av = a[r][c];
                axp[r] += av.x*x4.x + av.y*x4.y + av.z*x4.z + av.w*x4.w;
            }
        }
        #pragma unroll
        for (int r = 0; r < 4; ++r) {
            RED16_ADD(axp[r]);
            if (j == 0) s_axc[wb + 4 * g + r] = axp[r];
        }
        __syncthreads();
    }

    // ------------------------------ main loop ------------------------------
    for (int k = 0; k < K_ITER; ++k) {
        if (t == 0) s_mask = 0xFFFFFFFFu;
        if (t < MM) s_w[t] = MU / fmaxf(s_bb[t] - s_axc[t], s_cl[t]);
        __syncthreads();

        // pass 1: gbar = A^T w  (registers, then shfl over g, then 8-wave LDS)
        {
            float4 gb[4];
            #pragma unroll
            for (int c = 0; c < 4; ++c) gb[c] = make_float4(0.f, 0.f, 0.f, 0.f);
            #pragma unroll
            for (int r = 0; r < 4; ++r) {
                const float wm = s_w[wb + 4 * g + r];
                #pragma unroll
                for (int c = 0; c < 4; ++c) {
                    gb[c].x += a[r][c].x * wm;
                    gb[c].y += a[r][c].y * wm;
                    gb[c].z += a[r][c].z * wm;
                    gb[c].w += a[r][c].w * wm;
                }
            }
            #pragma unroll
            for (int c = 0; c < 4; ++c) {
                REDG_ADD(gb[c].x); REDG_ADD(gb[c].y); REDG_ADD(gb[c].z); REDG_ADD(gb[c].w);
            }
            if (g == 0) {
                #pragma unroll
                for (int c = 0; c < 4; ++c)
                    ((float4*)s_p1[wave])[j + 16 * c] = gb[c];
            }
        }
        __syncthreads();

        // grad + n-side line-search mask
        if (t < NN) {
            float gsum = 0.f;
            #pragma unroll
            for (int w = 0; w < 8; ++w) gsum += s_p1[w][t];
            const float xt = s_x[t];
            const float gr = (xt - s_xraw[t]) + gsum + MU / fmaxf(xt - s_lower[t], 1e-12f);
            s_grad[t] = gr;
            unsigned mn = 0u;
            const float loe = s_lower[t] + EPS;
            float st = 1.0f;
            #pragma unroll
            for (int l = 0; l < MAX_LS; ++l) {
                if (xt - st * gr >= loe) mn |= (1u << l);
                st *= 0.5f;
            }
            RED64_AND(mn);
            if (lane == 0) atomicAnd(&s_mask, mn);
        }
        __syncthreads();

        // pass 2: pg = A*grad, px = A*x (fresh), from registers
        {
            float pg[4] = {0.f,0.f,0.f,0.f}, px[4] = {0.f,0.f,0.f,0.f};
            #pragma unroll
            for (int c = 0; c < 4; ++c) {
                const float4 g4 = ((const float4*)s_grad)[j + 16 * c];
                const float4 x4 = ((const float4*)s_x)[j + 16 * c];
                #pragma unroll
                for (int r = 0; r < 4; ++r) {
                    const float4 av = a[r][c];
                    pg[r] += av.x*g4.x + av.y*g4.y + av.z*g4.z + av.w*g4.w;
                    px[r] += av.x*x4.x + av.y*x4.y + av.z*x4.z + av.w*x4.w;
                }
            }
            #pragma unroll
            for (int r = 0; r < 4; ++r) {
                RED16_ADD(pg[r]); RED16_ADD(px[r]);
                if (j == 0) { const int m = wb + 4 * g + r; s_pg[m] = pg[r]; s_px[m] = px[r]; }
            }
        }
        __syncthreads();

        // m-side line-search mask
        if (t < MM) {
            const float pgm = s_pg[t], pxm = s_px[t], cem = s_ce[t];
            unsigned mmk = 0u;
            float st = 1.0f;
            #pragma unroll
            for (int l = 0; l < MAX_LS; ++l) {
                if (pxm - st * pgm <= cem) mmk |= (1u << l);
                st *= 0.5f;
            }
            RED64_AND(mmk);
            if (lane == 0) atomicAnd(&s_mask, mmk);
        }
        __syncthreads();

        // ---- grid consensus: OR cleared bits up a 2-level tree, publish ----
        if (t == 0) {
            const unsigned bad = (~s_mask) & FULLMASK;     // cleared bits
            unsigned* leaf = wsu + W_LEAF(k, p >> 4);
            __hip_atomic_fetch_or(leaf, bad, __ATOMIC_RELAXED, __HIP_MEMORY_SCOPE_AGENT);
            asm volatile("s_waitcnt vmcnt(0)" ::: "memory");
            const unsigned larr = __hip_atomic_fetch_add(leaf + 8, 1u,
                                    __ATOMIC_RELAXED, __HIP_MEMORY_SCOPE_AGENT);
            if (larr == GSZ - 1u) {
                const unsigned lor = __hip_atomic_load(leaf,
                                        __ATOMIC_RELAXED, __HIP_MEMORY_SCOPE_AGENT);
                __hip_atomic_fetch_or(&wsu[W_ROOT_OR(k)], lor,
                                      __ATOMIC_RELAXED, __HIP_MEMORY_SCOPE_AGENT);
                asm volatile("s_waitcnt vmcnt(0)" ::: "memory");
                const unsigned rarr = __hip_atomic_fetch_add(&wsu[W_ROOT_CNT(k)], 1u,
                                        __ATOMIC_RELAXED, __HIP_MEMORY_SCOPE_AGENT);
                if (rarr == GRPS - 1u) {
                    const unsigned ror = __hip_atomic_load(&wsu[W_ROOT_OR(k)],
                                            __ATOMIC_RELAXED, __HIP_MEMORY_SCOPE_AGENT);
                    const unsigned gm = FULLMASK & ~ror;
                    __hip_atomic_store(&wsu[W_RES(k)], gm | DONEBIT,
                                       __ATOMIC_RELAXED, __HIP_MEMORY_SCOPE_AGENT);
                }
            }
            unsigned r;
            while (!((r = __hip_atomic_load(&wsu[W_RES(k)],
                            __ATOMIC_RELAXED, __HIP_MEMORY_SCOPE_AGENT)) & DONEBIT))
                __builtin_amdgcn_s_sleep(1);
            const unsigned gm = r & FULLMASK;
            s_step = gm ? ldexpf(1.0f, -(__ffs(gm) - 1)) : 0.0f;
        }
        __syncthreads();
        const float step = s_step;
        if (t < NN) s_x[t]  -= step * s_grad[t];
        if (t < MM) s_axc[t] = s_px[t] - step * s_pg[t];
        // next iteration's first __syncthreads orders these writes before reads
    }

    if (t < NN) out_g[p * NN + t] = fmaxf(s_x[t], 0.0f);
}

// -------------------------------------------------------------- launch ----
extern "C" void kernel_launch(void* const* d_in, const int* in_sizes, int n_in,
                              void* d_out, int out_size, void* d_ws, size_t ws_size,
                              hipStream_t stream) {
    const float* xraw  = (const float*)d_in[0];
    const float* A     = (const float*)d_in[1];
    const float* b     = (const float*)d_in[2];
    const float* lower = (const float*)d_in[3];
    float* out = (float*)d_out;
    unsigned* wsu = (unsigned*)d_ws;

    lbp_ws_init<<<(W_END + 1023) / 1024, 1024, 0, stream>>>(wsu);
    lbp_fused<<<NPROB, NTHR, 0, stream>>>(xraw, A, b, lower, out, wsu);
}

// Round 5
// 307.681 us; speedup vs baseline: 2.8018x; 1.0807x over previous
//
#include <hip/hip_runtime.h>

#define K_ITER   30
#define MU       0.01f
#define EPS      1e-6f
#define MAX_LS   25
#define FULLMASK 0x01FFFFFFu
#define MM       128
#define NN       256
#define NPROB    512
#define NTHR     512          // 8 waves/block; launch_bounds(512,4) -> 2 blocks/CU guaranteed

// ---- ws layout (unsigned words); zero-initialized each launch ----
// flag[p]  : one 128B line per block: ((k+1)<<25) | bad-bits   (written by block p)
// bcast[i] : 16 lines: ((k+1)<<25) | gm                        (written by master)
#define LSTRIDE 32
#define NBC     16
#define W_FLAG(p)  ((p)*LSTRIDE)
#define W_BCAST(i) (NPROB*LSTRIDE + (i)*LSTRIDE)
#define W_END      (NPROB*LSTRIDE + NBC*LSTRIDE)   // 16896 words

// --- cross-lane reduce helpers -------------------------------------------
#define RED16_ADD(v) do { v += __shfl_xor(v, 1); v += __shfl_xor(v, 2); \
                          v += __shfl_xor(v, 4); v += __shfl_xor(v, 8); } while (0)
#define REDG_ADD(v)  do { v += __shfl_xor(v, 16); v += __shfl_xor(v, 32); } while (0)
#define RED64_AND(v) do { v &= __shfl_xor(v, 1);  v &= __shfl_xor(v, 2);  v &= __shfl_xor(v, 4); \
                          v &= __shfl_xor(v, 8);  v &= __shfl_xor(v, 16); v &= __shfl_xor(v, 32); } while (0)
#define RED64_OR(v)  do { v |= __shfl_xor(v, 1);  v |= __shfl_xor(v, 2);  v |= __shfl_xor(v, 4); \
                          v |= __shfl_xor(v, 8);  v |= __shfl_xor(v, 16); v |= __shfl_xor(v, 32); } while (0)
#define RED64_MIN(v) do { v = fminf(v, __shfl_xor(v, 1));  v = fminf(v, __shfl_xor(v, 2)); \
                          v = fminf(v, __shfl_xor(v, 4));  v = fminf(v, __shfl_xor(v, 8)); \
                          v = fminf(v, __shfl_xor(v, 16)); v = fminf(v, __shfl_xor(v, 32)); } while (0)

#define AGLOAD(p)     __hip_atomic_load((p),      __ATOMIC_RELAXED, __HIP_MEMORY_SCOPE_AGENT)
#define AGSTORE(p, v) __hip_atomic_store((p), (v), __ATOMIC_RELAXED, __HIP_MEMORY_SCOPE_AGENT)

// -------------------------------------------------------- ws clear ----
__global__ void lbp_ws_init(unsigned* __restrict__ wsu)
{
    const int idx = blockIdx.x * 1024 + threadIdx.x;
    if (idx < W_END) wsu[idx] = 0u;
}

// Persistent kernel: block p owns problem p; A slice lives in 64 regs/thread.
// Lane (g=lane>>4, j=lane&15) of wave w holds rows 16w+4g+r (r=0..3) and col
// chunks [4j+64c .. 4j+64c+3] (c=0..3).
// Per-iteration grid consensus: every block stores tag|bad to its own flag
// line (relaxed agent store, payload travels in-word -> no fences needed);
// block 0's 512 threads poll the 512 distinct lines in parallel (s_sleep
// backoff to avoid MALL load storms), OR-reduce via shuffles, and publish
// tag|gm to 16 broadcast lines.  No RMW atomics anywhere on the barrier path.
__global__ __launch_bounds__(NTHR, 4)
void lbp_fused(const float* __restrict__ xraw_g,
               const float* __restrict__ A_g,
               const float* __restrict__ b_g,
               const float* __restrict__ lower_g,
               float* __restrict__ out_g,
               unsigned* __restrict__ wsu)
{
    const int p    = blockIdx.x;
    const int t    = threadIdx.x;
    const int lane = t & 63;
    const int wave = t >> 6;          // 0..7
    const int g    = lane >> 4;       // 0..3  row sub-group
    const int j    = lane & 15;       // 0..15 col sub-group
    const int wb   = wave * 16;       // wave's base row

    const float* A = A_g + (size_t)p * (MM * NN);

    __shared__ __align__(16) float s_x[NN];
    __shared__ __align__(16) float s_grad[NN];
    __shared__ __align__(16) float s_xraw[NN];
    __shared__ __align__(16) float s_lower[NN];
    __shared__ __align__(16) float s_p1[8][NN];            // per-wave A^T w partials
    __shared__ float s_bb[MM], s_cl[MM], s_ce[MM], s_w[MM];
    __shared__ float s_axc[MM], s_pg[MM], s_px[MM];
    __shared__ float s_rs[MM], s_al[MM], s_ssq[MM];        // init only
    __shared__ float s_redw[2];
    __shared__ unsigned s_redu[8];
    __shared__ unsigned s_mask, s_gm;
    __shared__ float s_step, s_t0;

    // ---- load A slice into registers (only HBM read of A in the solve) ----
    float4 a[4][4];
    {
        const float* base = A + (size_t)(wb + 4 * g) * NN + 4 * j;
        #pragma unroll
        for (int r = 0; r < 4; ++r)
            #pragma unroll
            for (int c = 0; c < 4; ++c)
                a[r][c] = *(const float4*)(base + r * NN + 64 * c);
    }

    if (t < NN) { s_xraw[t] = xraw_g[p * NN + t]; s_lower[t] = lower_g[p * NN + t]; }
    if (t < MM) s_bb[t] = b_g[p * MM + t];
    __syncthreads();

    // ---- init: row stats (ssq, rowsum, A·lower) from registers ----
    {
        float ssq[4] = {0.f,0.f,0.f,0.f}, rs[4] = {0.f,0.f,0.f,0.f}, al[4] = {0.f,0.f,0.f,0.f};
        #pragma unroll
        for (int c = 0; c < 4; ++c) {
            const float4 lo4 = ((const float4*)s_lower)[j + 16 * c];
            #pragma unroll
            for (int r = 0; r < 4; ++r) {
                const float4 av = a[r][c];
                ssq[r] += av.x*av.x + av.y*av.y + av.z*av.z + av.w*av.w;
                rs[r]  += av.x + av.y + av.z + av.w;
                al[r]  += av.x*lo4.x + av.y*lo4.y + av.z*lo4.z + av.w*lo4.w;
            }
        }
        #pragma unroll
        for (int r = 0; r < 4; ++r) {
            RED16_ADD(ssq[r]); RED16_ADD(rs[r]); RED16_ADD(al[r]);
            if (j == 0) {
                const int m = wb + 4 * g + r;
                s_ssq[m] = ssq[r]; s_rs[m] = rs[r]; s_al[m] = al[r];
            }
        }
    }
    __syncthreads();

    if (t < MM) {
        const float r = fmaxf(sqrtf(s_ssq[t]), 1e-12f);
        s_cl[t] = 1e-12f * r;                    // slack clamp (unnormalized)
        s_ce[t] = s_bb[t] - EPS * r;             // feasibility threshold
        const float adw = s_rs[t] / r;
        const float sw  = (s_bb[t] - s_al[t]) / r;
        float ratio = (adw > 0.f) ? (sw / fmaxf(adw, 1e-12f)) : INFINITY;
        RED64_MIN(ratio);
        if (lane == 0) s_redw[wave] = ratio;
    }
    __syncthreads();
    if (t == 0) s_t0 = fmaxf(0.5f * fminf(s_redw[0], s_redw[1]), 2.0f * EPS);
    __syncthreads();
    const float t0 = s_t0;
    if (t < NN) s_x[t]   = s_lower[t] + t0;
    if (t < MM) s_axc[t] = s_al[t] + t0 * s_rs[t];

    // feasibility repair (faithful; no-op for these inputs)
    int okf = 1;
    if (t < MM) okf = okf && (s_axc[t] <= s_ce[t]);
    if (t < NN) okf = okf && (s_x[t] >= s_lower[t] + EPS);
    const int feas = __syncthreads_and(okf);
    if (!feas) {
        if (t < NN) s_x[t] = 0.5f * (fmaxf(s_x[t], 0.f) + s_lower[t]);
        __syncthreads();
        float axp[4] = {0.f,0.f,0.f,0.f};
        #pragma unroll
        for (int c = 0; c < 4; ++c) {
            const float4 x4 = ((const float4*)s_x)[j + 16 * c];
            #pragma unroll
            for (int r = 0; r < 4; ++r) {
                const float4 av = a[r][c];
                axp[r] += av.x*x4.x + av.y*x4.y + av.z*x4.z + av.w*x4.w;
            }
        }
        #pragma unroll
        for (int r = 0; r < 4; ++r) {
            RED16_ADD(axp[r]);
            if (j == 0) s_axc[wb + 4 * g + r] = axp[r];
        }
        __syncthreads();
    }

    // ------------------------------ main loop ------------------------------
    for (int k = 0; k < K_ITER; ++k) {
        if (t == 0) s_mask = 0xFFFFFFFFu;
        if (t < MM) s_w[t] = MU / fmaxf(s_bb[t] - s_axc[t], s_cl[t]);
        __syncthreads();

        // pass 1: gbar = A^T w  (registers, then shfl over g, then 8-wave LDS)
        {
            float4 gb[4];
            #pragma unroll
            for (int c = 0; c < 4; ++c) gb[c] = make_float4(0.f, 0.f, 0.f, 0.f);
            #pragma unroll
            for (int r = 0; r < 4; ++r) {
                const float wm = s_w[wb + 4 * g + r];
                #pragma unroll
                for (int c = 0; c < 4; ++c) {
                    gb[c].x += a[r][c].x * wm;
                    gb[c].y += a[r][c].y * wm;
                    gb[c].z += a[r][c].z * wm;
                    gb[c].w += a[r][c].w * wm;
                }
            }
            #pragma unroll
            for (int c = 0; c < 4; ++c) {
                REDG_ADD(gb[c].x); REDG_ADD(gb[c].y); REDG_ADD(gb[c].z); REDG_ADD(gb[c].w);
            }
            if (g == 0) {
                #pragma unroll
                for (int c = 0; c < 4; ++c)
                    ((float4*)s_p1[wave])[j + 16 * c] = gb[c];
            }
        }
        __syncthreads();

        // grad + n-side line-search mask
        if (t < NN) {
            float gsum = 0.f;
            #pragma unroll
            for (int w = 0; w < 8; ++w) gsum += s_p1[w][t];
            const float xt = s_x[t];
            const float gr = (xt - s_xraw[t]) + gsum + MU / fmaxf(xt - s_lower[t], 1e-12f);
            s_grad[t] = gr;
            unsigned mn = 0u;
            const float loe = s_lower[t] + EPS;
            float st = 1.0f;
            #pragma unroll
            for (int l = 0; l < MAX_LS; ++l) {
                if (xt - st * gr >= loe) mn |= (1u << l);
                st *= 0.5f;
            }
            RED64_AND(mn);
            if (lane == 0) atomicAnd(&s_mask, mn);
        }
        __syncthreads();

        // pass 2: pg = A*grad, px = A*x (fresh), from registers
        {
            float pg[4] = {0.f,0.f,0.f,0.f}, px[4] = {0.f,0.f,0.f,0.f};
            #pragma unroll
            for (int c = 0; c < 4; ++c) {
                const float4 g4 = ((const float4*)s_grad)[j + 16 * c];
                const float4 x4 = ((const float4*)s_x)[j + 16 * c];
                #pragma unroll
                for (int r = 0; r < 4; ++r) {
                    const float4 av = a[r][c];
                    pg[r] += av.x*g4.x + av.y*g4.y + av.z*g4.z + av.w*g4.w;
                    px[r] += av.x*x4.x + av.y*x4.y + av.z*x4.z + av.w*x4.w;
                }
            }
            #pragma unroll
            for (int r = 0; r < 4; ++r) {
                RED16_ADD(pg[r]); RED16_ADD(px[r]);
                if (j == 0) { const int m = wb + 4 * g + r; s_pg[m] = pg[r]; s_px[m] = px[r]; }
            }
        }
        __syncthreads();

        // m-side line-search mask
        if (t < MM) {
            const float pgm = s_pg[t], pxm = s_px[t], cem = s_ce[t];
            unsigned mmk = 0u;
            float st = 1.0f;
            #pragma unroll
            for (int l = 0; l < MAX_LS; ++l) {
                if (pxm - st * pgm <= cem) mmk |= (1u << l);
                st *= 0.5f;
            }
            RED64_AND(mmk);
            if (lane == 0) atomicAnd(&s_mask, mmk);
        }
        __syncthreads();

        // ---- grid consensus: flag-store + master OR-reduce + broadcast ----
        const unsigned tag = (unsigned)(k + 1) << 25;
        if (p == 0) {
            // master: each thread owns one flag line (t==0 uses local mask)
            unsigned bad;
            if (t == 0) {
                bad = (~s_mask) & FULLMASK;
            } else {
                unsigned v;
                while ((((v = AGLOAD(&wsu[W_FLAG(t)])) >> 25)) != (unsigned)(k + 1))
                    __builtin_amdgcn_s_sleep(1);
                bad = v & FULLMASK;
            }
            RED64_OR(bad);
            if (lane == 0) s_redu[wave] = bad;
            __syncthreads();
            if (t == 0) {
                unsigned orall = 0u;
                #pragma unroll
                for (int w = 0; w < 8; ++w) orall |= s_redu[w];
                const unsigned gm = FULLMASK & ~orall;
                s_gm   = gm;
                s_step = gm ? ldexpf(1.0f, -(__ffs(gm) - 1)) : 0.0f;
            }
            __syncthreads();
            if (t < NBC) AGSTORE(&wsu[W_BCAST(t)], tag | s_gm);
        } else {
            if (t == 0) {
                AGSTORE(&wsu[W_FLAG(p)], tag | ((~s_mask) & FULLMASK));
                unsigned v;
                while ((((v = AGLOAD(&wsu[W_BCAST(p & (NBC - 1))])) >> 25)) != (unsigned)(k + 1))
                    __builtin_amdgcn_s_sleep(1);
                const unsigned gm = v & FULLMASK;
                s_step = gm ? ldexpf(1.0f, -(__ffs(gm) - 1)) : 0.0f;
            }
            __syncthreads();
        }
        const float step = s_step;
        if (t < NN) s_x[t]  -= step * s_grad[t];
        if (t < MM) s_axc[t] = s_px[t] - step * s_pg[t];
        // next iteration's first __syncthreads orders these writes before reads
    }

    if (t < NN) out_g[p * NN + t] = fmaxf(s_x[t], 0.0f);
}

// -------------------------------------------------------------- launch ----
extern "C" void kernel_launch(void* const* d_in, const int* in_sizes, int n_in,
                              void* d_out, int out_size, void* d_ws, size_t ws_size,
                              hipStream_t stream) {
    const float* xraw  = (const float*)d_in[0];
    const float* A     = (const float*)d_in[1];
    const float* b     = (const float*)d_in[2];
    const float* lower = (const float*)d_in[3];
    float* out = (float*)d_out;
    unsigned* wsu = (unsigned*)d_ws;

    lbp_ws_init<<<(W_END + 1023) / 1024, 1024, 0, stream>>>(wsu);
    lbp_fused<<<NPROB, NTHR, 0, stream>>>(xraw, A, b, lower, out, wsu);
}